// Round 1
// baseline (538.569 us; speedup 1.0000x reference)
//
#include <hip/hip_runtime.h>

#define N_NODES 100000
#define N_EDGES 1600000
#define ELL_W 64

// Build ELL adjacency (dst -> list of src) + degree histograms.
__global__ __launch_bounds__(256) void k_build(const int* __restrict__ src, const int* __restrict__ dst,
                                               int* __restrict__ out_deg, int* __restrict__ fill,
                                               int* __restrict__ ell) {
    int e = blockIdx.x * 256 + threadIdx.x;
    if (e >= N_EDGES) return;
    int s = src[e];
    int d = dst[e];
    atomicAdd(&out_deg[s], 1);
    int p = atomicAdd(&fill[d], 1);
    if (p < ELL_W) ell[d * ELL_W + p] = s;
}

__global__ __launch_bounds__(256) void k_norm(const int* __restrict__ out_deg, const int* __restrict__ fill,
                                              float* __restrict__ norm_src, float* __restrict__ norm_dst) {
    int i = blockIdx.x * 256 + threadIdx.x;
    if (i >= N_NODES) return;
    int od = out_deg[i]; if (od < 1) od = 1;
    int id = fill[i];    if (id < 1) id = 1;
    norm_src[i] = rsqrtf((float)od);
    norm_dst[i] = rsqrtf((float)id);
}

// Y[r][c] = norm[r] * sum_k X[r][k] * W[k][c]   (X: M x K row-major, W: K x NCOL row-major)
// 64-row tile per block, 256 threads, 4x4 register micro-tile.
template<int K, int NCOL>
__global__ __launch_bounds__(256) void k_gemm(const float* __restrict__ X, const float* __restrict__ W,
                                              const float* __restrict__ norm, float* __restrict__ Y) {
    __shared__ float Xt[K][64];   // transposed X tile: Xt[k][row]
    __shared__ float Wl[K][64];   // W tile, cols padded to 64 with zeros
    const int tid = threadIdx.x;
    const int row0 = blockIdx.x * 64;

    for (int idx = tid; idx < K * 64; idx += 256) {
        int k = idx >> 6, c = idx & 63;
        Wl[k][c] = (c < NCOL) ? W[k * NCOL + c] : 0.0f;
    }
    {
        int r = tid & 63;
        int gr = row0 + r;
        for (int kq = tid >> 6; kq < K / 4; kq += 4) {
            float4 v = make_float4(0.f, 0.f, 0.f, 0.f);
            if (gr < N_NODES) v = *(const float4*)(X + (long)gr * K + kq * 4);
            Xt[kq * 4 + 0][r] = v.x;
            Xt[kq * 4 + 1][r] = v.y;
            Xt[kq * 4 + 2][r] = v.z;
            Xt[kq * 4 + 3][r] = v.w;
        }
    }
    __syncthreads();

    const int rb = (tid >> 4) << 2;   // 0..60
    const int cb = (tid & 15) << 2;   // 0..60
    float acc[4][4] = {};
    #pragma unroll 4
    for (int k = 0; k < K; ++k) {
        float4 x4 = *(const float4*)&Xt[k][rb];
        float4 w4 = *(const float4*)&Wl[k][cb];
        float xv[4] = {x4.x, x4.y, x4.z, x4.w};
        float wv[4] = {w4.x, w4.y, w4.z, w4.w};
        #pragma unroll
        for (int i = 0; i < 4; ++i)
            #pragma unroll
            for (int j = 0; j < 4; ++j)
                acc[i][j] += xv[i] * wv[j];
    }

    if (cb < NCOL) {
        #pragma unroll
        for (int i = 0; i < 4; ++i) {
            int gr = row0 + rb + i;
            if (gr < N_NODES) {
                float s = norm[gr];
                float4 o;
                o.x = acc[i][0] * s; o.y = acc[i][1] * s;
                o.z = acc[i][2] * s; o.w = acc[i][3] * s;
                *(float4*)(Y + (long)gr * NCOL + cb) = o;
            }
        }
    }
}

// OUT[d][:] = act( norm_dst[d] * sum_{s in ell[d]} XW[s][:] + bias )
// One thread per (node, float4 feature quad).
template<int NF, bool RELU>
__global__ __launch_bounds__(256) void k_agg(const float* __restrict__ XW, const int* __restrict__ ell,
                                             const int* __restrict__ deg, const float* __restrict__ norm_dst,
                                             const float* __restrict__ bias, float* __restrict__ OUT) {
    constexpr int NQ = NF / 4;
    int gid = blockIdx.x * 256 + threadIdx.x;
    int d = gid / NQ;
    int q = gid - d * NQ;
    if (d >= N_NODES) return;
    int dg = deg[d]; if (dg > ELL_W) dg = ELL_W;
    const int* el = ell + (long)d * ELL_W;
    float a0 = 0.f, a1 = 0.f, a2 = 0.f, a3 = 0.f;
    for (int j = 0; j < dg; ++j) {
        int s = el[j];
        float4 v = *(const float4*)(XW + (long)s * NF + q * 4);
        a0 += v.x; a1 += v.y; a2 += v.z; a3 += v.w;
    }
    float nd = norm_dst[d];
    float o0 = a0 * nd + bias[q * 4 + 0];
    float o1 = a1 * nd + bias[q * 4 + 1];
    float o2 = a2 * nd + bias[q * 4 + 2];
    float o3 = a3 * nd + bias[q * 4 + 3];
    if (RELU) {
        o0 = fmaxf(o0, 0.f); o1 = fmaxf(o1, 0.f);
        o2 = fmaxf(o2, 0.f); o3 = fmaxf(o3, 0.f);
    }
    *(float4*)(OUT + (long)d * NF + q * 4) = make_float4(o0, o1, o2, o3);
}

extern "C" void kernel_launch(void* const* d_in, const int* in_sizes, int n_in,
                              void* d_out, int out_size, void* d_ws, size_t ws_size,
                              hipStream_t stream) {
    const float* h  = (const float*)d_in[0];
    const float* W0 = (const float*)d_in[1];
    const float* b0 = (const float*)d_in[2];
    const float* W1 = (const float*)d_in[3];
    const float* b1 = (const float*)d_in[4];
    const float* W2 = (const float*)d_in[5];
    const float* b2 = (const float*)d_in[6];
    const int* src  = (const int*)d_in[7];
    const int* dst  = (const int*)d_in[8];
    float* out = (float*)d_out;

    char* ws = (char*)d_ws;
    size_t off = 0;
    int* fill        = (int*)(ws + off); off += (size_t)N_NODES * 4;        // doubles as in_deg
    int* out_deg     = (int*)(ws + off); off += (size_t)N_NODES * 4;
    float* norm_src  = (float*)(ws + off); off += (size_t)N_NODES * 4;
    float* norm_dst  = (float*)(ws + off); off += (size_t)N_NODES * 4;
    int* ell         = (int*)(ws + off); off += (size_t)N_NODES * ELL_W * 4;
    float* bufA      = (float*)(ws + off); off += (size_t)N_NODES * 64 * 4;
    float* bufB      = (float*)(ws + off); off += (size_t)N_NODES * 64 * 4;

    // fill + out_deg are contiguous: one memset clears both.
    hipMemsetAsync(fill, 0, (size_t)N_NODES * 8, stream);

    k_build<<<(N_EDGES + 255) / 256, 256, 0, stream>>>(src, dst, out_deg, fill, ell);
    k_norm<<<(N_NODES + 255) / 256, 256, 0, stream>>>(out_deg, fill, norm_src, norm_dst);

    // Layer 0: h [100000x128] @ W0 [128x64] -> bufA; gather -> bufB (ReLU)
    k_gemm<128, 64><<<(N_NODES + 63) / 64, 256, 0, stream>>>(h, W0, norm_src, bufA);
    k_agg<64, true><<<(N_NODES * 16 + 255) / 256, 256, 0, stream>>>(bufA, ell, fill, norm_dst, b0, bufB);

    // Layer 1: bufB @ W1 [64x64] -> bufA; gather -> bufB (ReLU)
    k_gemm<64, 64><<<(N_NODES + 63) / 64, 256, 0, stream>>>(bufB, W1, norm_src, bufA);
    k_agg<64, true><<<(N_NODES * 16 + 255) / 256, 256, 0, stream>>>(bufA, ell, fill, norm_dst, b1, bufB);

    // Layer 2: bufB @ W2 [64x40] -> bufA (stride 40); gather -> out (no act)
    k_gemm<64, 40><<<(N_NODES + 63) / 64, 256, 0, stream>>>(bufB, W2, norm_src, bufA);
    k_agg<40, false><<<(N_NODES * 10 + 255) / 256, 256, 0, stream>>>(bufA, ell, fill, norm_dst, b2, out);
}

// Round 2
// 499.789 us; speedup vs baseline: 1.0776x; 1.0776x over previous
//
#include <hip/hip_runtime.h>

#define N_NODES 100000
#define N_EDGES 1600000
#define ELL_W 64

// Build transposed ELL adjacency (ell[slot * N_NODES + dst] = src) + degree histograms.
// Transposed layout: slot-p writes land in a dense 400 KB stripe -> L2 line coalescing
// instead of one HBM line write-back per edge (R1: WRITE_SIZE was 146 MB row-major).
__global__ __launch_bounds__(256) void k_build(const int* __restrict__ src, const int* __restrict__ dst,
                                               int* __restrict__ out_deg, int* __restrict__ fill,
                                               int* __restrict__ ell) {
    int e = blockIdx.x * 256 + threadIdx.x;
    if (e >= N_EDGES) return;
    int s = src[e];
    int d = dst[e];
    atomicAdd(&out_deg[s], 1);                 // fire-and-forget
    int p = atomicAdd(&fill[d], 1);            // must wait for slot
    if (p < ELL_W) ell[p * N_NODES + d] = s;   // transposed scatter
}

__global__ __launch_bounds__(256) void k_norm(const int* __restrict__ out_deg, const int* __restrict__ fill,
                                              float* __restrict__ norm_src, float* __restrict__ norm_dst) {
    int i = blockIdx.x * 256 + threadIdx.x;
    if (i >= N_NODES) return;
    int od = out_deg[i]; if (od < 1) od = 1;
    int id = fill[i];    if (id < 1) id = 1;
    norm_src[i] = rsqrtf((float)od);
    norm_dst[i] = rsqrtf((float)id);
}

// Y[r][c] = norm[r] * sum_k X[r][k] * W[k][c]   (X: M x K row-major, W: K x NCOL row-major)
// 64-row tile per block, 256 threads, 4x4 register micro-tile.
template<int K, int NCOL>
__global__ __launch_bounds__(256) void k_gemm(const float* __restrict__ X, const float* __restrict__ W,
                                              const float* __restrict__ norm, float* __restrict__ Y) {
    __shared__ float Xt[K][64];   // transposed X tile: Xt[k][row]
    __shared__ float Wl[K][64];   // W tile, cols padded to 64 with zeros
    const int tid = threadIdx.x;
    const int row0 = blockIdx.x * 64;

    for (int idx = tid; idx < K * 64; idx += 256) {
        int k = idx >> 6, c = idx & 63;
        Wl[k][c] = (c < NCOL) ? W[k * NCOL + c] : 0.0f;
    }
    {
        int r = tid & 63;
        int gr = row0 + r;
        for (int kq = tid >> 6; kq < K / 4; kq += 4) {
            float4 v = make_float4(0.f, 0.f, 0.f, 0.f);
            if (gr < N_NODES) v = *(const float4*)(X + (long)gr * K + kq * 4);
            Xt[kq * 4 + 0][r] = v.x;
            Xt[kq * 4 + 1][r] = v.y;
            Xt[kq * 4 + 2][r] = v.z;
            Xt[kq * 4 + 3][r] = v.w;
        }
    }
    __syncthreads();

    const int rb = (tid >> 4) << 2;   // 0..60
    const int cb = (tid & 15) << 2;   // 0..60
    float acc[4][4] = {};
    #pragma unroll 4
    for (int k = 0; k < K; ++k) {
        float4 x4 = *(const float4*)&Xt[k][rb];
        float4 w4 = *(const float4*)&Wl[k][cb];
        float xv[4] = {x4.x, x4.y, x4.z, x4.w};
        float wv[4] = {w4.x, w4.y, w4.z, w4.w};
        #pragma unroll
        for (int i = 0; i < 4; ++i)
            #pragma unroll
            for (int j = 0; j < 4; ++j)
                acc[i][j] += xv[i] * wv[j];
    }

    if (cb < NCOL) {
        #pragma unroll
        for (int i = 0; i < 4; ++i) {
            int gr = row0 + rb + i;
            if (gr < N_NODES) {
                float s = norm[gr];
                float4 o;
                o.x = acc[i][0] * s; o.y = acc[i][1] * s;
                o.z = acc[i][2] * s; o.w = acc[i][3] * s;
                *(float4*)(Y + (long)gr * NCOL + cb) = o;
            }
        }
    }
}

// OUT[d][:] = act( norm_dst[d] * sum_{s in ell[d]} XW[s][:] + bias )
// One thread per (node, float4 feature quad). Transposed ELL; gather loop
// unrolled x4: 4 independent index loads then 4 independent gathers -> 4x MLP.
template<int NF, bool RELU>
__global__ __launch_bounds__(256) void k_agg(const float* __restrict__ XW, const int* __restrict__ ell,
                                             const int* __restrict__ deg, const float* __restrict__ norm_dst,
                                             const float* __restrict__ bias, float* __restrict__ OUT) {
    constexpr int NQ = NF / 4;
    int gid = blockIdx.x * 256 + threadIdx.x;
    int d = gid / NQ;
    int q = gid - d * NQ;
    if (d >= N_NODES) return;
    int dg = deg[d]; if (dg > ELL_W) dg = ELL_W;

    float a0 = 0.f, a1 = 0.f, a2 = 0.f, a3 = 0.f;
    int j = 0;
    for (; j + 4 <= dg; j += 4) {
        int i0 = ell[(j + 0) * N_NODES + d];
        int i1 = ell[(j + 1) * N_NODES + d];
        int i2 = ell[(j + 2) * N_NODES + d];
        int i3 = ell[(j + 3) * N_NODES + d];
        float4 v0 = *(const float4*)(XW + (long)i0 * NF + q * 4);
        float4 v1 = *(const float4*)(XW + (long)i1 * NF + q * 4);
        float4 v2 = *(const float4*)(XW + (long)i2 * NF + q * 4);
        float4 v3 = *(const float4*)(XW + (long)i3 * NF + q * 4);
        a0 += v0.x + v1.x + v2.x + v3.x;
        a1 += v0.y + v1.y + v2.y + v3.y;
        a2 += v0.z + v1.z + v2.z + v3.z;
        a3 += v0.w + v1.w + v2.w + v3.w;
    }
    for (; j < dg; ++j) {
        int s = ell[j * N_NODES + d];
        float4 v = *(const float4*)(XW + (long)s * NF + q * 4);
        a0 += v.x; a1 += v.y; a2 += v.z; a3 += v.w;
    }

    float nd = norm_dst[d];
    float o0 = a0 * nd + bias[q * 4 + 0];
    float o1 = a1 * nd + bias[q * 4 + 1];
    float o2 = a2 * nd + bias[q * 4 + 2];
    float o3 = a3 * nd + bias[q * 4 + 3];
    if (RELU) {
        o0 = fmaxf(o0, 0.f); o1 = fmaxf(o1, 0.f);
        o2 = fmaxf(o2, 0.f); o3 = fmaxf(o3, 0.f);
    }
    *(float4*)(OUT + (long)d * NF + q * 4) = make_float4(o0, o1, o2, o3);
}

extern "C" void kernel_launch(void* const* d_in, const int* in_sizes, int n_in,
                              void* d_out, int out_size, void* d_ws, size_t ws_size,
                              hipStream_t stream) {
    const float* h  = (const float*)d_in[0];
    const float* W0 = (const float*)d_in[1];
    const float* b0 = (const float*)d_in[2];
    const float* W1 = (const float*)d_in[3];
    const float* b1 = (const float*)d_in[4];
    const float* W2 = (const float*)d_in[5];
    const float* b2 = (const float*)d_in[6];
    const int* src  = (const int*)d_in[7];
    const int* dst  = (const int*)d_in[8];
    float* out = (float*)d_out;

    char* ws = (char*)d_ws;
    size_t off = 0;
    int* fill        = (int*)(ws + off); off += (size_t)N_NODES * 4;        // doubles as in_deg
    int* out_deg     = (int*)(ws + off); off += (size_t)N_NODES * 4;
    float* norm_src  = (float*)(ws + off); off += (size_t)N_NODES * 4;
    float* norm_dst  = (float*)(ws + off); off += (size_t)N_NODES * 4;
    int* ell         = (int*)(ws + off); off += (size_t)N_NODES * ELL_W * 4;  // transposed [ELL_W][N_NODES]
    float* bufA      = (float*)(ws + off); off += (size_t)N_NODES * 64 * 4;
    float* bufB      = (float*)(ws + off); off += (size_t)N_NODES * 64 * 4;

    // fill + out_deg are contiguous: one memset clears both.
    hipMemsetAsync(fill, 0, (size_t)N_NODES * 8, stream);

    k_build<<<(N_EDGES + 255) / 256, 256, 0, stream>>>(src, dst, out_deg, fill, ell);
    k_norm<<<(N_NODES + 255) / 256, 256, 0, stream>>>(out_deg, fill, norm_src, norm_dst);

    // Layer 0: h [100000x128] @ W0 [128x64] -> bufA; gather -> bufB (ReLU)
    k_gemm<128, 64><<<(N_NODES + 63) / 64, 256, 0, stream>>>(h, W0, norm_src, bufA);
    k_agg<64, true><<<(N_NODES * 16 + 255) / 256, 256, 0, stream>>>(bufA, ell, fill, norm_dst, b0, bufB);

    // Layer 1: bufB @ W1 [64x64] -> bufA; gather -> bufB (ReLU)
    k_gemm<64, 64><<<(N_NODES + 63) / 64, 256, 0, stream>>>(bufB, W1, norm_src, bufA);
    k_agg<64, true><<<(N_NODES * 16 + 255) / 256, 256, 0, stream>>>(bufA, ell, fill, norm_dst, b1, bufB);

    // Layer 2: bufB @ W2 [64x40] -> bufA (stride 40); gather -> out (no act)
    k_gemm<64, 40><<<(N_NODES + 63) / 64, 256, 0, stream>>>(bufB, W2, norm_src, bufA);
    k_agg<40, false><<<(N_NODES * 10 + 255) / 256, 256, 0, stream>>>(bufA, ell, fill, norm_dst, b2, out);
}